// Round 9
// baseline (999.073 us; speedup 1.0000x reference)
//
#include <hip/hip_runtime.h>
#include <stdint.h>

#define C_ITEMS 16384
#define NCLS 16
#define HSTRIDE 16386   // AP hist entries per class (opt in [1, P+1])
#define BSTRIDE 16386   // B-table entries per class
#define PCAP 2048       // LDS posrank fast-path limit (actual P ~1024)
#define NBLK 1024       // 4 blocks/CU exact fit; co-residency via __launch_bounds__(256,4)
#define GENBASE 0x10000000u

// ---- workspace layout (bytes) ----
static const size_t OFF_COL  = 0;                                     // 16*16384 f32 col-major scores
static const size_t OFF_SPOS = 1u << 20;                              // sorted positives (desc) per class
static const size_t OFF_SMV  = 2u << 20;                              // negatives ascending by rank
static const size_t OFF_PACK = 3u << 20;                              // bucket-scattered (low16key,idx)
static const size_t OFF_HIST = 4u << 20;                              // 16 * HSTRIDE u32 (AP hist)
static const size_t OFF_ACCS = OFF_HIST + (size_t)NCLS * HSTRIDE * 4; // 16 double
static const size_t OFF_ACCV = OFF_ACCS + 128;                        // 16 double
static const size_t OFF_TOT  = OFF_ACCV + 128;                        // 1 double
static const size_t OFF_PC   = OFF_TOT + 8;                           // 16 u32 positive counters
static const size_t OFF_H1   = (OFF_PC + 64 + 255) & ~(size_t)255;    // 16 * 65536 u32 bucket hist
static const size_t OFF_PPK  = OFF_H1 + (((size_t)NCLS << 16) * 4);   // 16 * 16384 u64 positive keys
// Overlays in the ppk region (ppk dead after posrank stage):
static const size_t OFF_HARM = OFF_PPK;                               // 16385 f32 harmonic table
static const size_t OFF_BS   = OFF_PPK + 0x12000;                     // 16 * BSTRIDE f32 B tables
static const size_t OFF_PART = OFF_BS + (size_t)NCLS * BSTRIDE * 4;   // 1024 u32 scan partials
static const size_t OFF_BAR  = OFF_PART + 4096;                       // 2 u32 barrier state (NOT zeroed)
static const size_t ZERO_BYTES = OFF_PPK - OFF_HIST;                  // zero hist..h1 (incl pcnt)

__device__ __forceinline__ unsigned ordkey(float f) {
  unsigned b = __float_as_uint(f);
  return (b & 0x80000000u) ? ~b : (b | 0x80000000u);   // monotone float->uint
}

__global__ __launch_bounds__(256, 4) void k_all(const float* __restrict__ scores,
    const int* __restrict__ labels, float* __restrict__ out, char* __restrict__ ws) {
  float* col      = (float*)(ws + OFF_COL);
  float* spos     = (float*)(ws + OFF_SPOS);
  float* smv      = (float*)(ws + OFF_SMV);
  unsigned* pack  = (unsigned*)(ws + OFF_PACK);
  unsigned* hist  = (unsigned*)(ws + OFF_HIST);
  double* accS    = (double*)(ws + OFF_ACCS);
  double* accV    = (double*)(ws + OFF_ACCV);
  double* total   = (double*)(ws + OFF_TOT);
  unsigned* pcnt  = (unsigned*)(ws + OFF_PC);
  unsigned* h1    = (unsigned*)(ws + OFF_H1);
  unsigned long long* ppk = (unsigned long long*)(ws + OFF_PPK);
  float* Hg       = (float*)(ws + OFF_HARM);
  float* Bsg      = (float*)(ws + OFF_BS);
  unsigned* part  = (unsigned*)(ws + OFF_PART);
  unsigned* bar   = (unsigned*)(ws + OFF_BAR);

  const int bx = blockIdx.x, tid = threadIdx.x;
  const int lane = tid & 63, w = tid >> 6;
  const int gtid = bx * 256 + tid;          // 0..262143 — exactly one per item*class

  __shared__ unsigned long long pk[PCAP];   // 16 KB (posrank)
  __shared__ unsigned su[256];
  __shared__ double sd[256];
  __shared__ int sh_i0, sh_i1;

  // ---- barrier init: handle 0xAA-poisoned ws without a separate launch ----
  if (tid == 0) {
    if (bx == 0) {
      atomicExch(&bar[0], 0u);
      __threadfence();
      atomicExch(&bar[1], GENBASE);
    }
    while (atomicAdd(&bar[1], 0u) != GENBASE) __builtin_amdgcn_s_sleep(1);
  }
  __syncthreads();
  unsigned gen = GENBASE;

  #define GBAR() do {                                                    \
    __syncthreads();                                                     \
    if (tid == 0) {                                                      \
      __threadfence();                                                   \
      ++gen;                                                             \
      unsigned t_ = atomicAdd(&bar[0], 1u);                              \
      if (t_ == NBLK - 1u) {                                             \
        atomicExch(&bar[0], 0u);                                         \
        __threadfence();                                                 \
        atomicAdd(&bar[1], 1u);                                          \
      } else {                                                           \
        while (atomicAdd(&bar[1], 0u) < gen) __builtin_amdgcn_s_sleep(1);\
      }                                                                  \
      __threadfence();                                                   \
    }                                                                    \
    __syncthreads();                                                     \
  } while (0)

  // ---- S0: zero hist..h1 (incl accS/accV/total/pcnt) ----
  {
    uint4* p = (uint4*)(ws + OFF_HIST);
    int n = (int)(ZERO_BYTES / 16);
    for (int t = gtid; t < n; t += NBLK * 256)
      p[t] = make_uint4(0u, 0u, 0u, 0u);
  }
  GBAR();

  // ---- S1: transpose + neg bucket hist + pos (key,idx) collect ----
  {
    int t = gtid;
    float v = scores[t];
    int i = t >> 4, c = t & 15;
    col[(c << 14) | i] = v;
    if (labels[i] != c) {
      atomicAdd(&h1[(c << 16) + (ordkey(v) >> 16)], 1u);
    } else {
      unsigned idx = atomicAdd(&pcnt[c], 1u);
      if (idx < 16384u)
        ppk[(c << 14) + idx] = ((unsigned long long)(~ordkey(v)) << 32) | (unsigned)i;
    }
  }
  GBAR();

  // ---- S2: scanA (units 0..1023) + posrank (units 1024..1087) ----
  for (int u = bx; u < 1088; u += NBLK) {
    __syncthreads();
    if (u < 1024) {
      int c = u >> 6, b = u & 63;
      const uint4* hp = (const uint4*)(h1 + ((size_t)c << 16) + b * 1024);
      uint4 v = hp[tid];
      su[tid] = v.x + v.y + v.z + v.w;
      __syncthreads();
      for (int off = 128; off > 0; off >>= 1) {
        if (tid < off) su[tid] += su[tid + off];
        __syncthreads();
      }
      if (tid == 0) part[c * 64 + b] = su[0];
    } else {
      int idx = u - 1024;
      int c = idx >> 2, sub = idx & 3;
      unsigned P = pcnt[c];
      const unsigned long long* src = ppk + ((size_t)c << 14);
      if (P <= PCAP) {
        for (unsigned t = tid; t < P; t += 256) pk[t] = src[t];
        __syncthreads();
        for (unsigned q = sub * 256 + tid; q < P; q += 1024) {
          unsigned long long k64 = pk[q];
          unsigned cq = 0;
          for (unsigned t = 0; t < P; ++t) cq += (pk[t] < k64) ? 1u : 0u;
          unsigned i = (unsigned)(k64 & 0xFFFFFFFFu);
          spos[(c << 14) + cq] = scores[i * NCLS + c];
        }
      } else {                            // safety fallback: global reads
        for (unsigned q = sub * 256 + tid; q < P; q += 1024) {
          unsigned long long k64 = src[q];
          unsigned cq = 0;
          for (unsigned t = 0; t < P; ++t) cq += (src[t] < k64) ? 1u : 0u;
          unsigned i = (unsigned)(k64 & 0xFFFFFFFFu);
          spos[(c << 14) + cq] = scores[i * NCLS + c];
        }
      }
    }
  }
  GBAR();

  // ---- S3: scanC (units 0..1023) + btab (1024..1039) + harm (1040) ----
  for (int u = bx; u < 1041; u += NBLK) {
    __syncthreads();
    if (u < 1024) {                       // scanC w/ inline partial-prefix
      int c = u >> 6, b = u & 63;
      if (tid < 64) {
        unsigned v = (tid < b) ? part[c * 64 + tid] : 0u;
        for (int off = 1; off < 64; off <<= 1) v += __shfl_xor(v, off, 64);
        if (tid == 0) sh_i0 = (int)v;
      }
      uint4* hp = (uint4*)(h1 + ((size_t)c << 16) + b * 1024);
      uint4 v = hp[tid];
      unsigned s = v.x + v.y + v.z + v.w;
      su[tid] = s;
      __syncthreads();
      for (int off = 1; off < 256; off <<= 1) {
        unsigned t2 = (tid >= off) ? su[tid - off] : 0u;
        __syncthreads();
        su[tid] += t2;
        __syncthreads();
      }
      unsigned base = (unsigned)sh_i0 + su[tid] - s;
      uint4 o;
      o.x = base; o.y = base + v.x; o.z = base + v.x + v.y; o.w = base + v.x + v.y + v.z;
      hp[tid] = o;
    } else if (u < 1040) {                // btab: Bs[r] = -(2/(PN)) * sum_{k>=r} sp_k
      int c = u - 1024;
      int P = (int)pcnt[c], N = C_ITEMS - P;
      if (P > 0 && N > 0) {
        int L = (P + 255) / 256;
        int a = tid * L, e = min(a + L, P);
        double s = 0.0;
        for (int q = a; q < e; ++q) s += (double)spos[(c << 14) + q];
        sd[tid] = s;
        __syncthreads();
        for (int off = 1; off < 256; off <<= 1) {
          double v = (tid >= off) ? sd[tid - off] : 0.0;
          __syncthreads();
          sd[tid] += v;
          __syncthreads();
        }
        double totalp = sd[255];
        double run = sd[tid] - s;
        double coefD = 2.0 / ((double)P * (double)N);
        for (int q = a; q < e; ++q) {
          Bsg[c * BSTRIDE + q + 1] = (float)(-coefD * (totalp - run));
          run += (double)spos[(c << 14) + q];
        }
        if (tid == 0) Bsg[c * BSTRIDE + P + 1] = 0.f;
      }
    } else {                              // harm: H[m] = sum_{t<=m} 1/t
      int m0 = tid * 64 + 1;
      double s = 0.0;
      for (int q = 0; q < 64; ++q) s += 1.0 / (double)(m0 + q);
      sd[tid] = s;
      __syncthreads();
      for (int off = 1; off < 256; off <<= 1) {
        double v = (tid >= off) ? sd[tid - off] : 0.0;
        __syncthreads();
        sd[tid] += v;
        __syncthreads();
      }
      double run = sd[tid] - s;
      for (int q = 0; q < 64; ++q) {
        run += 1.0 / (double)(m0 + q);
        Hg[m0 + q] = (float)run;
      }
      if (tid == 0) Hg[0] = 0.f;
    }
  }
  GBAR();

  // ---- S4: scatter negatives; h1[b] becomes bucket END ----
  {
    int t = gtid;
    int c = t >> 14, i = t & 16383;
    if (labels[i] != c) {
      unsigned k = ordkey(col[t]);
      unsigned p = atomicAdd(&h1[(c << 16) + (k >> 16)], 1u);
      pack[(c << 14) + p] = (k << 16) | (unsigned)i;
    }
  }
  GBAR();

  // ---- S5: fine rank -> smv[rank] = value ----
  {
    int t = gtid;
    int c = t >> 14, i = t & 16383;
    if (labels[i] != c) {
      float v = col[t];
      unsigned k = ordkey(v);
      unsigned b = k >> 16;
      const unsigned* hb = h1 + ((size_t)c << 16);
      unsigned start = b ? hb[b - 1] : 0u;
      unsigned end = hb[b];
      unsigned mine = (k << 16) | (unsigned)i;
      const unsigned* pkg = pack + (c << 14);
      unsigned cnt = start;
      for (unsigned q = start; q < end; ++q) cnt += (pkg[q] < mine) ? 1u : 0u;
      smv[(c << 14) + cnt] = v;
    }
  }
  GBAR();

  // ---- S6: bracketed argmax. Unit = 256 j's. Waves 0/1: bracketing pivots
  // (full wave-parallel scans); then thread = one j, serial scan over [lo,hi].
  // f(r) = Bs[r] - r*cj - invP*H[j0+r]; first-max; Monge: opt_j non-decreasing.
  for (int u = bx; u < 1024; u += NBLK) {
    int c = u >> 6;
    int P = (int)pcnt[c], N = C_ITEMS - P;
    int jb = (u & 63) << 8;
    if (P == 0 || N == 0 || jb >= N) continue;   // block-uniform
    __syncthreads();
    float invP = 1.0f / (float)P;
    float coef = 2.0f / ((float)P * (float)N);
    const float* Bp = Bsg + c * BSTRIDE;
    if (w < 2) {
      int j0p = jb + (w << 8);          // jb or jb+256
      int res = P + 1;
      if (j0p < N) {
        float v = smv[(c << 14) + j0p];
        float cj = coef * v;
        const float* Hp = Hg + j0p;
        float bestf = -3.3e38f, bestr = 1.0f;
        int nch = (P + 64) >> 6;
        for (int ch = 0; ch < nch; ++ch) {
          int r = 1 + (ch << 6) + lane;
          float f = -3.0e38f;
          if (r <= P + 1)
            f = fmaf(-invP, Hp[r], fmaf(-cj, (float)r, Bp[r]));
          bool g = f > bestf;           // strict: first max wins ties
          bestf = g ? f : bestf;
          bestr = g ? (float)r : bestr;
        }
        for (int off = 1; off < 64; off <<= 1) {
          float of = __shfl_xor(bestf, off, 64);
          float orf = __shfl_xor(bestr, off, 64);
          bool take = (of > bestf) || (of == bestf && orf < bestr);
          bestf = take ? of : bestf;
          bestr = take ? orf : bestr;
        }
        res = (int)bestr;
      }
      if (lane == 0) { if (w == 0) sh_i0 = res; else sh_i1 = res; }
    }
    __syncthreads();
    int lo = sh_i0, hi = sh_i1;
    if (hi < lo) { int t = lo; lo = hi; hi = t; }   // f32-noise guard
    int j0 = jb + tid;
    bool act = (j0 < N);
    float v = 0.f;
    int besti = lo;
    if (act) {
      v = smv[(c << 14) + j0];
      float cj = coef * v;
      const float* Hp = Hg + j0;        // Hp[r]: lane-consecutive, coalesced
      float bestf = -3.3e38f;
      for (int r = lo; r <= hi; ++r) {
        float f = fmaf(-invP, Hp[r], fmaf(-cj, (float)r, Bp[r]));
        if (f > bestf) { bestf = f; besti = r; }    // strict: first max
      }
      atomicAdd(&hist[c * HSTRIDE + besti], 1u);
    }
    double s1 = act ? (double)(P + 2 - 2 * besti) * (double)v : 0.0;
    double s2 = act ? (double)v : 0.0;
    sd[tid] = s1; __syncthreads();
    for (int s = 128; s > 0; s >>= 1) { if (tid < s) sd[tid] += sd[tid + s]; __syncthreads(); }
    if (tid == 0) atomicAdd(&accS[c], sd[0]);
    __syncthreads();
    sd[tid] = s2; __syncthreads();
    for (int s = 128; s > 0; s >>= 1) { if (tid < s) sd[tid] += sd[tid + s]; __syncthreads(); }
    if (tid == 0) atomicAdd(&accV[c], sd[0]);
  }
  GBAR();

  // ---- S7: per-class finalize (blocks 0..15) ----
  if (bx < NCLS) {
    int c = bx;
    int P = (int)pcnt[c], N = C_ITEMS - P;
    if (P > 0 && N > 0) {
      const unsigned* h = hist + c * HSTRIDE;
      int M = P + 1;
      int L = (M + 255) / 256;
      int o0 = 1 + tid * L;
      int o1 = min(o0 + L, P + 2);
      unsigned partv = 0;
      for (int o = o0; o < o1; ++o) partv += h[o];
      su[tid] = partv;
      __syncthreads();
      if (tid == 0) {
        unsigned runp = 0;
        for (int t = 0; t < 256; ++t) { unsigned tmp = su[t]; su[t] = runp; runp += tmp; }
      }
      __syncthreads();
      unsigned run = su[tid];
      double a1 = 0.0, a2 = 0.0, a3 = 0.0;
      for (int o = o0; o < o1; ++o) {
        run += h[o];
        if (o <= P) {
          int k0 = o - 1;
          double rp = 1.0 + (double)run;
          double spv = (double)spos[(c << 14) + k0];
          a1 += (double)(k0 + 1) / ((double)k0 + rp);
          a2 += spv * ((double)N + 2.0 - 2.0 * rp);
          a3 += spv;
        }
      }
      sd[tid] = a1; __syncthreads();
      for (int s = 128; s > 0; s >>= 1) { if (tid < s) sd[tid] += sd[tid + s]; __syncthreads(); }
      double r1 = sd[0]; __syncthreads();
      sd[tid] = a2; __syncthreads();
      for (int s = 128; s > 0; s >>= 1) { if (tid < s) sd[tid] += sd[tid + s]; __syncthreads(); }
      double r2 = sd[0]; __syncthreads();
      sd[tid] = a3; __syncthreads();
      for (int s = 128; s > 0; s >>= 1) { if (tid < s) sd[tid] += sd[tid + s]; __syncthreads(); }
      double r3 = sd[0];
      if (tid == 0) {
        double Pd = (double)P, Nd = (double)N;
        double FR  = r2 + accS[c];
        double FRs = Nd * r3 - Pd * accV[c];
        double lc  = (1.0 - r1 / Pd) + (FR - FRs) / (Pd * Nd);
        atomicAdd(total, lc);
      }
    }
  }
  GBAR();
  if (bx == 0 && tid == 0)
    out[0] = (float)(atomicAdd(total, 0.0) / (double)NCLS);
  #undef GBAR
}

extern "C" void kernel_launch(void* const* d_in, const int* in_sizes, int n_in,
                              void* d_out, int out_size, void* d_ws, size_t ws_size,
                              hipStream_t stream) {
  (void)in_sizes; (void)n_in; (void)out_size; (void)ws_size;
  const float* scores = (const float*)d_in[0];
  const int* labels = (const int*)d_in[1];
  float* out = (float*)d_out;
  char* ws = (char*)d_ws;
  k_all<<<NBLK, 256, 0, stream>>>(scores, labels, out, ws);
}